// Round 2
// baseline (598.467 us; speedup 1.0000x reference)
//
#include <hip/hip_runtime.h>

#define NN 100000
#define NSTEP 5
#define LSTR 264   // ushorts; 528B rows, 16B aligned for ds_read_b128
#define NT_FNN 1563
#define NB_FNN 512

typedef unsigned short ushort_t;
typedef __attribute__((ext_vector_type(8))) short short8;
typedef __attribute__((ext_vector_type(4))) float floatx4;

__device__ __forceinline__ ushort_t f2bf(float f){
  union { float f; unsigned u; } v; v.f = f;
  unsigned r = v.u + 0x7fffu + ((v.u >> 16) & 1u);
  return (ushort_t)(r >> 16);
}
__device__ __forceinline__ float bf2f(ushort_t s){
  union { unsigned u; float f; } v; v.u = ((unsigned)s) << 16;
  return v.f;
}
__device__ __forceinline__ float sigf(float x){ return 1.0f/(1.0f+__expf(-x)); }

// ================= fused FNN: hfeat = (elu(x@W1+b1))@W2+b2, bf16 out =================
// Persistent: 512 blocks x 512 thr (8 waves), 3-4 tiles each, (512,2) => 256-VGPR cap so the
// compiler can software-pipeline (R0/R1 ran at 36-64 VGPR: every load was waited immediately
// => latency-serialized at 80us with all pipes <20%). Wave = 32 rows x 64 cols (acc[2][4]):
// halves LDS af traffic vs R1. Staging is register-double-buffered (issue-early/write-late):
// next tile's 8 float4 loads are issued before GEMM1 and drained after GEMM2.
__global__ __launch_bounds__(512, 2) void fnn_fused(const float* __restrict__ x,
    const ushort_t* __restrict__ W1P, const float* __restrict__ b1,
    const ushort_t* __restrict__ W2P, const float* __restrict__ b2,
    ushort_t* __restrict__ hfeat, int M)
{
  __shared__ ushort_t buf[64 * LSTR];
  int tid = threadIdx.x;
  int lane = tid & 63, qd = lane >> 4, r16 = lane & 15;
  int w = tid >> 6;
  int rh = w >> 2, cg = w & 3;          // wave: rows rh*32+[0,32), cols cg*64+[0,64)

  // per-wave bias values: cols constant across tiles -> hoist
  float bb1[4], bb2[4];
  #pragma unroll
  for (int j = 0; j < 4; j++){
    int col = cg*64 + j*16 + r16;
    bb1[j] = b1[col];
    bb2[j] = b2[col];
  }

  int t = blockIdx.x;
  float4 xv[8];

  // prologue: stage tile t
  {
    int row0 = t * 64;
    #pragma unroll
    for (int it = 0; it < 8; it++){
      int idx = it*512 + tid;
      int rg = row0 + (idx>>6); if (rg >= M) rg = M-1;
      xv[it] = *(const float4*)(x + (size_t)rg*256 + (idx&63)*4);
    }
    #pragma unroll
    for (int it = 0; it < 8; it++){
      int idx = it*512 + tid;
      ushort4 pk = make_ushort4(f2bf(xv[it].x), f2bf(xv[it].y), f2bf(xv[it].z), f2bf(xv[it].w));
      *(ushort4*)&buf[(idx>>6)*LSTR + (idx&63)*4] = pk;
    }
    __syncthreads();
  }

  for (; t < NT_FNN; t += NB_FNN){
    int tn = t + NB_FNN;
    // ---- issue next tile's global loads (drain after GEMM2) ----
    if (tn < NT_FNN){
      int row0n = tn * 64;
      #pragma unroll
      for (int it = 0; it < 8; it++){
        int idx = it*512 + tid;
        int rg = row0n + (idx>>6); if (rg >= M) rg = M-1;
        xv[it] = *(const float4*)(x + (size_t)rg*256 + (idx&63)*4);
      }
    }

    floatx4 acc[2][4];
    // ---- GEMM1 ----
    #pragma unroll
    for (int i=0;i<2;i++)
      #pragma unroll
      for (int j=0;j<4;j++) acc[i][j] = (floatx4){0.f,0.f,0.f,0.f};
    #pragma unroll
    for (int kc = 0; kc < 8; kc++){
      short8 af[2], bfr[4];
      #pragma unroll
      for (int i=0;i<2;i++)
        af[i] = *(const short8*)&buf[(rh*32 + i*16 + r16) * LSTR + kc*32 + qd*8];
      #pragma unroll
      for (int j=0;j<4;j++)
        bfr[j] = *(const short8*)(W1P + (size_t)(((cg*4 + j)*8 + kc)*64 + lane)*8);
      #pragma unroll
      for (int i=0;i<2;i++)
        #pragma unroll
        for (int j=0;j<4;j++)
          acc[i][j] = __builtin_amdgcn_mfma_f32_16x16x32_bf16(af[i], bfr[j], acc[i][j], 0, 0, 0);
    }
    __syncthreads();   // A: GEMM1 reads done -> safe to overwrite buf with t-tile

    // ---- ELU -> t tile (overwrites x tile in LDS) ----
    #pragma unroll
    for (int i=0;i<2;i++){
      #pragma unroll
      for (int j=0;j<4;j++){
        int col = cg*64 + j*16 + r16;
        #pragma unroll
        for (int rr=0;rr<4;rr++){
          int row = rh*32 + i*16 + qd*4 + rr;
          float v = acc[i][j][rr] + bb1[j];
          v = v > 0.f ? v : (__expf(v) - 1.0f);
          buf[row * LSTR + col] = f2bf(v);
        }
      }
    }
    __syncthreads();   // B: t tile visible

    // ---- GEMM2 ----
    #pragma unroll
    for (int i=0;i<2;i++)
      #pragma unroll
      for (int j=0;j<4;j++) acc[i][j] = (floatx4){0.f,0.f,0.f,0.f};
    #pragma unroll
    for (int kc = 0; kc < 8; kc++){
      short8 af[2], bfr[4];
      #pragma unroll
      for (int i=0;i<2;i++)
        af[i] = *(const short8*)&buf[(rh*32 + i*16 + r16) * LSTR + kc*32 + qd*8];
      #pragma unroll
      for (int j=0;j<4;j++)
        bfr[j] = *(const short8*)(W2P + (size_t)(((cg*4 + j)*8 + kc)*64 + lane)*8);
      #pragma unroll
      for (int i=0;i<2;i++)
        #pragma unroll
        for (int j=0;j<4;j++)
          acc[i][j] = __builtin_amdgcn_mfma_f32_16x16x32_bf16(af[i], bfr[j], acc[i][j], 0, 0, 0);
    }

    // ---- epilogue: hfeat store ----
    {
      int row0 = t * 64;
      #pragma unroll
      for (int i=0;i<2;i++){
        #pragma unroll
        for (int j=0;j<4;j++){
          int col = cg*64 + j*16 + r16;
          #pragma unroll
          for (int rr=0;rr<4;rr++){
            int row = row0 + rh*32 + i*16 + qd*4 + rr;
            if (row < M) hfeat[(size_t)row * 256 + col] = f2bf(acc[i][j][rr] + bb2[j]);
          }
        }
      }
    }
    __syncthreads();   // C: GEMM2 reads done -> safe to overwrite buf with x(t+NB)

    if (tn < NT_FNN){
      #pragma unroll
      for (int it = 0; it < 8; it++){
        int idx = it*512 + tid;
        ushort4 pk = make_ushort4(f2bf(xv[it].x), f2bf(xv[it].y), f2bf(xv[it].z), f2bf(xv[it].w));
        *(ushort4*)&buf[(idx>>6)*LSTR + (idx&63)*4] = pk;
      }
    }
    __syncthreads();   // D: x(t+NB) visible for next GEMM1
  }
}

// ================= LSTM layer: gates GEMM (K-split x4 waves) + fused cell =================
// 128 blocks x 256. Block = (m0 = 16 rows, nt = 16 h-cols) x 4 gates. Weights fragment-major.
__global__ __launch_bounds__(256) void lstm_layer(const ushort_t* __restrict__ A, int lda,
    const ushort_t* __restrict__ WcP, const float* __restrict__ bcp, int KC,
    float* __restrict__ c, ushort_t* __restrict__ dstA, int sA,
    ushort_t* __restrict__ dstB, int sB, float* __restrict__ qdst)
{
  __shared__ float sbuf[3][4][256];
  int tid = threadIdx.x, w = tid >> 6, lane = tid & 63, qd = lane >> 4, r16 = lane & 15;
  int m0 = (blockIdx.x & 7) * 16, nt = blockIdx.x >> 3;
  int kcq = KC >> 2;                       // chunks per wave: 6 (K=768) or 4 (K=512)
  int kc0 = w * kcq;

  floatx4 acc[4];
  #pragma unroll
  for (int g=0; g<4; g++) acc[g] = (floatx4){0.f,0.f,0.f,0.f};

  const ushort_t* Ar = A + (size_t)(m0 + r16) * lda + qd * 8;
  for (int kc = kc0; kc < kc0 + kcq; kc++){
    short8 av = *(const short8*)(Ar + kc*32);
    #pragma unroll
    for (int g = 0; g < 4; g++){
      short8 bv = *(const short8*)(WcP + (size_t)((((g*16 + nt)*KC) + kc)*64 + lane)*8);
      acc[g] = __builtin_amdgcn_mfma_f32_16x16x32_bf16(av, bv, acc[g], 0, 0, 0);
    }
  }
  if (w){
    #pragma unroll
    for (int g=0; g<4; g++) *(floatx4*)&sbuf[w-1][g][lane*4] = acc[g];
  }
  __syncthreads();
  if (w == 0){
    #pragma unroll
    for (int g=0; g<4; g++)
      #pragma unroll
      for (int t=0; t<3; t++){
        floatx4 p = *(floatx4*)&sbuf[t][g][lane*4];
        acc[g] = acc[g] + p;
      }
    int h = nt*16 + r16;
    float bci = bcp[h], bcf = bcp[256+h], bcg = bcp[512+h], bco = bcp[768+h];
    #pragma unroll
    for (int rr=0; rr<4; rr++){
      int row = m0 + qd*4 + rr;
      float gi = acc[0][rr] + bci;
      float gf = acc[1][rr] + bcf;
      float gg = acc[2][rr] + bcg;
      float go = acc[3][rr] + bco;
      float cp = c[row*256 + h];
      float cn = sigf(gf)*cp + sigf(gi)*tanhf(gg);
      float hn = sigf(go)*tanhf(cn);
      c[row*256 + h] = cn;
      ushort_t hb = f2bf(hn);
      dstA[row*sA + h] = hb;
      dstB[row*sB + h] = hb;
      if (qdst) qdst[row*512 + h] = hn;
    }
  }
}

// ================= one-pass attention: S[b] += exp(e_n)*h_n, Z[b] += exp(e_n) =================
// 1024 blocks x 256 thr: 4096 waves, wave = 25 contiguous (sorted) nodes, prefetch depth 2
// (more waves/CU + deeper outstanding loads to cover ~900cy HBM latency). No max-subtract
// (|e| ~ O(10) << 88, fp32 exp safe); softmax normalization happens in attn_fin.
__global__ __launch_bounds__(256) void attn_onepass(const ushort_t* __restrict__ hfeat,
    const int* __restrict__ bidx, const float* __restrict__ q_star,
    float* __restrict__ r_acc, float* __restrict__ z_acc)
{
  const int CH = (NN + 4095) / 4096;       // 25
  int gw = blockIdx.x*4 + (threadIdx.x >> 6);
  int lane = threadIdx.x & 63;
  int n0 = gw * CH;
  int nend = n0 + CH; if (nend > NN) nend = NN;
  if (n0 >= nend) return;

  int bcur = bidx[n0];
  float4 q = *(const float4*)(q_star + (size_t)bcur*512 + lane*4);
  float S0=0.f, S1=0.f, S2=0.f, S3=0.f, Z=0.f;

  // depth-2 pipeline: h0v = node n, h1v = node n+1 in flight
  ushort4 h0v = *(const ushort4*)(hfeat + (size_t)n0*256 + lane*4);
  ushort4 h1v = h0v; int b1v = bcur;
  if (n0 + 1 < nend){
    h1v = *(const ushort4*)(hfeat + (size_t)(n0+1)*256 + lane*4);
    b1v = bidx[n0+1];
  }
  for (int n = n0; n < nend; n++){
    ushort4 h2v = h1v; int b2v = b1v;
    if (n + 2 < nend){
      h2v = *(const ushort4*)(hfeat + (size_t)(n+2)*256 + lane*4);
      b2v = bidx[n+2];
    }
    float f0 = bf2f(h0v.x), f1 = bf2f(h0v.y), f2 = bf2f(h0v.z), f3 = bf2f(h0v.w);
    float d = f0*q.x + f1*q.y + f2*q.z + f3*q.w;
    #pragma unroll
    for (int off = 32; off; off >>= 1) d += __shfl_xor(d, off);
    float wgt = __expf(d);
    Z += wgt;
    S0 += wgt*f0; S1 += wgt*f1; S2 += wgt*f2; S3 += wgt*f3;
    int bn = (n + 1 < nend) ? b1v : bcur;
    if (bn != bcur){
      float* rp = r_acc + bcur*256 + lane*4;
      atomicAdd(rp+0, S0); atomicAdd(rp+1, S1);
      atomicAdd(rp+2, S2); atomicAdd(rp+3, S3);
      if (lane == 0) atomicAdd(&z_acc[bcur], Z);
      S0=S1=S2=S3=Z=0.f;
      bcur = bn;
      q = *(const float4*)(q_star + (size_t)bcur*512 + lane*4);
    }
    h0v = h1v; h1v = h2v; b1v = b2v;
  }
  float* rp = r_acc + bcur*256 + lane*4;
  atomicAdd(rp+0, S0); atomicAdd(rp+1, S1);
  atomicAdd(rp+2, S2); atomicAdd(rp+3, S3);
  if (lane == 0) atomicAdd(&z_acc[bcur], Z);
}

// ================= finalize: r = S/Z -> q_star/xc0; zero acc; last: output GEMM =================
__global__ __launch_bounds__(256) void attn_fin(float* __restrict__ r_acc,
    float* __restrict__ z_acc, float* __restrict__ q_star, ushort_t* __restrict__ xc0,
    const float* __restrict__ outW, const float* __restrict__ outb,
    float* __restrict__ out, int last)
{
  __shared__ float qs[512];
  int b = blockIdx.x, f = threadIdx.x;
  float v = r_acc[b*256 + f] / (z_acc[b] + 1e-16f);
  q_star[b*512 + 256 + f] = v;
  xc0[b*768 + 256 + f] = f2bf(v);
  r_acc[b*256 + f] = 0.f;
  if (f == 0) z_acc[b] = 0.f;
  if (last){
    qs[f] = q_star[b*512 + f];     // q half (written by lstm2, prior dispatch)
    qs[256 + f] = v;               // r half (computed here)
    __syncthreads();
    if (f < 128){
      float acc = outb[f];
      for (int k = 0; k < 512; k++) acc += qs[k] * outW[k*128 + f];
      out[b*128 + f] = acc;
    }
  }
}

// ================= prep: fragment-major weight packing + all zero/init =================
// Packed layout per 16-col tile T, 32-k chunk kc: [(T*KC + kc)*64 + lane]*8 + j,
// where lane holds BT[n = T*16 + (lane&15)][k = kc*32 + (lane>>4)*8 + j].
__global__ void prep_all(const float* __restrict__ W1, const float* __restrict__ W2,
    const float* __restrict__ Wih0, const float* __restrict__ Whh0,
    const float* __restrict__ Wih1, const float* __restrict__ Whh1,
    const float* __restrict__ Wih2, const float* __restrict__ Whh2,
    const float* __restrict__ bih0, const float* __restrict__ bhh0,
    const float* __restrict__ bih1, const float* __restrict__ bhh1,
    const float* __restrict__ bih2, const float* __restrict__ bhh2,
    const int* __restrict__ bidx,
    ushort_t* __restrict__ W1P, ushort_t* __restrict__ W2P,
    ushort_t* __restrict__ Wc0P, ushort_t* __restrict__ Wc1P, ushort_t* __restrict__ Wc2P,
    float* __restrict__ c, ushort_t* __restrict__ xc, float* __restrict__ q_star,
    float* __restrict__ bc, int* __restrict__ seg,
    float* __restrict__ r_acc, float* __restrict__ z_acc)
{
  int i = blockIdx.x*256 + threadIdx.x;
  // --- W1P / W2P: K=256, KC=8, tile size 4096 ---
  if (i < 131072){
    const float* W = (i < 65536) ? W1 : W2;
    ushort_t* P = (i < 65536) ? W1P : W2P;
    int r = i & 65535;
    int T = r >> 12, r2 = r & 4095;
    int kc = r2 >> 9, l = (r2 >> 3) & 63, j = r2 & 7;
    int k = kc*32 + ((l>>4)<<3) + j;
    int n = T*16 + (l & 15);
    P[r] = f2bf(W[k*256 + n]);
    return;
  }
  i -= 131072;
  // --- Wc0P: K=768, KC=24, tile size 12288, 64 tiles ---
  if (i < 786432){
    int T = i / 12288, r2 = i - T*12288;
    int kc = r2 >> 9, l = (r2 >> 3) & 63, j = r2 & 7;
    int k = kc*32 + ((l>>4)<<3) + j;
    int g = T >> 4, n = (T & 15)*16 + (l & 15);
    int row = g*256 + n;
    Wc0P[i] = f2bf(k < 512 ? Wih0[row*512 + k] : Whh0[row*256 + (k - 512)]);
    return;
  }
  i -= 786432;
  // --- Wc1P / Wc2P: K=512, KC=16, tile size 8192, 64 tiles each ---
  if (i < 1048576){
    const float* Wih = (i < 524288) ? Wih1 : Wih2;
    const float* Whh = (i < 524288) ? Whh1 : Whh2;
    ushort_t* P = (i < 524288) ? Wc1P : Wc2P;
    int r = i & 524287;
    int T = r >> 13, r2 = r & 8191;
    int kc = r2 >> 9, l = (r2 >> 3) & 63, j = r2 & 7;
    int k = kc*32 + ((l>>4)<<3) + j;
    int g = T >> 4, n = (T & 15)*16 + (l & 15);
    int row = g*256 + n;
    P[r] = f2bf(k < 256 ? Wih[row*256 + k] : Whh[row*256 + (k - 256)]);
    return;
  }
  i -= 1048576;
  if (i < 98304) { c[i] = 0.f; return; }
  i -= 98304;
  if (i < 229376) { xc[i] = 0; return; }
  i -= 229376;
  if (i < 65536) { q_star[i] = 0.f; return; }
  i -= 65536;
  if (i < 3072) {
    int l = i >> 10, g = i & 1023;
    const float* bi = (l == 0) ? bih0 : ((l == 1) ? bih1 : bih2);
    const float* bh = (l == 0) ? bhh0 : ((l == 1) ? bhh1 : bhh2);
    bc[i] = bi[g] + bh[g];
    return;
  }
  i -= 3072;
  if (i < 129) {
    int lo = 0, hi = NN;
    while (lo < hi){ int mid = (lo + hi) >> 1; if (bidx[mid] < i) lo = mid + 1; else hi = mid; }
    seg[i] = lo;
    return;
  }
  i -= 129;
  if (i < 32768) { r_acc[i] = 0.f; return; }
  i -= 32768;
  if (i < 128) z_acc[i] = 0.f;
}

extern "C" void kernel_launch(void* const* d_in, const int* in_sizes, int n_in,
                              void* d_out, int out_size, void* d_ws, size_t ws_size,
                              hipStream_t stream)
{
  const float* x    = (const float*)d_in[0];
  const int*   bidx = (const int*)  d_in[1];
  const float* W1   = (const float*)d_in[2];
  const float* b1   = (const float*)d_in[3];
  const float* W2   = (const float*)d_in[4];
  const float* b2   = (const float*)d_in[5];
  const float* Wih0 = (const float*)d_in[6];
  const float* Whh0 = (const float*)d_in[7];
  const float* bih0 = (const float*)d_in[8];
  const float* bhh0 = (const float*)d_in[9];
  const float* Wih1 = (const float*)d_in[10];
  const float* Whh1 = (const float*)d_in[11];
  const float* bih1 = (const float*)d_in[12];
  const float* bhh1 = (const float*)d_in[13];
  const float* Wih2 = (const float*)d_in[14];
  const float* Whh2 = (const float*)d_in[15];
  const float* bih2 = (const float*)d_in[16];
  const float* bhh2 = (const float*)d_in[17];
  const float* outW = (const float*)d_in[18];
  const float* outb = (const float*)d_in[19];

  char* p = (char*)d_ws;
  auto alloc = [&](size_t bytes)->char*{ char* r = p; p += (bytes + 255) & ~(size_t)255; return r; };
  ushort_t* hfeat  = (ushort_t*)alloc((size_t)NN*256*2);   // bf16 node features
  ushort_t* W1P    = (ushort_t*)alloc(65536*2);
  ushort_t* W2P    = (ushort_t*)alloc(65536*2);
  ushort_t* Wc0P   = (ushort_t*)alloc(786432*2);
  ushort_t* Wc1P   = (ushort_t*)alloc(524288*2);
  ushort_t* Wc2P   = (ushort_t*)alloc(524288*2);
  float*    bc     = (float*)   alloc(3072*4);
  float*    c_all  = (float*)   alloc(98304*4);
  ushort_t* xc     = (ushort_t*)alloc(229376*2);           // xc0(128x768)|xc1(128x512)|xc2(128x512)
  float*    q_star = (float*)   alloc(65536*4);            // (128,512) fp32
  float*    r_acc  = (float*)   alloc(32768*4);            // (128,256) fp32
  float*    z_acc  = (float*)   alloc(128*4);
  int*      seg    = (int*)     alloc(129*4);

  ushort_t* xc0 = xc;
  ushort_t* xc1 = xc + 98304;
  ushort_t* xc2 = xc + 163840;
  float* c0 = c_all, *c1 = c_all + 32768, *c2 = c_all + 65536;
  float* bc0 = bc, *bc1 = bc + 1024, *bc2 = bc + 2048;

  prep_all<<<9357, 256, 0, stream>>>(W1, W2, Wih0, Whh0, Wih1, Whh1, Wih2, Whh2,
                                     bih0, bhh0, bih1, bhh1, bih2, bhh2, bidx,
                                     W1P, W2P, Wc0P, Wc1P, Wc2P,
                                     c_all, xc, q_star, bc, seg, r_acc, z_acc);

  fnn_fused<<<NB_FNN, 512, 0, stream>>>(x, W1P, b1, W2P, b2, hfeat, NN);

  for (int s = 0; s < NSTEP; s++){
    // layer 0: in = [q_star | h0_prev] (K=768, KC=24)
    lstm_layer<<<128, 256, 0, stream>>>(xc0, 768, Wc0P, bc0, 24, c0, xc0 + 512, 768, xc1, 512, nullptr);
    // layer 1: in = [h0 | h1_prev] (K=512, KC=16)
    lstm_layer<<<128, 256, 0, stream>>>(xc1, 512, Wc1P, bc1, 16, c1, xc1 + 256, 512, xc2, 512, nullptr);
    // layer 2: in = [h1 | h2_prev] (K=512); h2 = q
    lstm_layer<<<128, 256, 0, stream>>>(xc2, 512, Wc2P, bc2, 16, c2, xc2 + 256, 512, xc0, 768, q_star);
    // one-pass attention + finalize (last step folds in the output GEMM)
    attn_onepass<<<1024, 256, 0, stream>>>(hfeat, bidx, q_star, r_acc, z_acc);
    attn_fin<<<128, 256, 0, stream>>>(r_acc, z_acc, q_star, xc0, outW, outb,
                                      (float*)d_out, s == NSTEP-1 ? 1 : 0);
  }
}

// Round 3
// 439.148 us; speedup vs baseline: 1.3628x; 1.3628x over previous
//
#include <hip/hip_runtime.h>

#define NN 100000
#define NSTEP 5
#define LSTR 264   // ushorts; 528B rows, 16B aligned for ds_read_b128

typedef unsigned short ushort_t;
typedef __attribute__((ext_vector_type(8))) short short8;
typedef __attribute__((ext_vector_type(4))) float floatx4;

__device__ __forceinline__ ushort_t f2bf(float f){
  union { float f; unsigned u; } v; v.f = f;
  unsigned r = v.u + 0x7fffu + ((v.u >> 16) & 1u);
  return (ushort_t)(r >> 16);
}
__device__ __forceinline__ float bf2f(ushort_t s){
  union { unsigned u; float f; } v; v.u = ((unsigned)s) << 16;
  return v.f;
}
__device__ __forceinline__ float sigf(float x){ return 1.0f/(1.0f+__expf(-x)); }

// ================= fused FNN: hfeat = (elu(x@W1+b1))@W2+b2, bf16 out =================
// 1563 blocks x 512 thr (8 waves), 64 rows x 256 cols, 33.8 KB LDS. R1 structure, but:
// #pragma unroll on kc loops + launch_bounds(512) [256-reg cap] so the compiler can keep
// weight loads in flight (R1 ran ROLLED at 36 VGPR = acc only = zero pipelining, all pipes
// <21%). Staging loads batched (xv[8] transient, dies at barrier -> no R2-style spill).
__global__ __launch_bounds__(512) void fnn_fused(const float* __restrict__ x,
    const ushort_t* __restrict__ W1P, const float* __restrict__ b1,
    const ushort_t* __restrict__ W2P, const float* __restrict__ b2,
    ushort_t* __restrict__ hfeat, int M)
{
  __shared__ ushort_t buf[64 * LSTR];
  int tid = threadIdx.x;
  int w = tid >> 6, lane = tid & 63, qd = lane >> 4, r16 = lane & 15;
  int row0 = blockIdx.x * 64;
  int col0 = w * 32;

  // ---- stage x tile: issue all 8 loads, then convert (xv dies before GEMM1) ----
  {
    float4 xv[8];
    #pragma unroll
    for (int it = 0; it < 8; it++){
      int idx = it * 512 + tid;
      int rg = row0 + (idx >> 6); if (rg >= M) rg = M - 1;
      xv[it] = *(const float4*)(x + (size_t)rg * 256 + (idx & 63) * 4);
    }
    #pragma unroll
    for (int it = 0; it < 8; it++){
      int idx = it * 512 + tid;
      ushort4 pk = make_ushort4(f2bf(xv[it].x), f2bf(xv[it].y), f2bf(xv[it].z), f2bf(xv[it].w));
      *(ushort4*)&buf[(idx >> 6) * LSTR + (idx & 63) * 4] = pk;
    }
  }
  __syncthreads();

  floatx4 acc[4][2];

  // ---- GEMM1 ----
  #pragma unroll
  for (int i=0;i<4;i++)
    #pragma unroll
    for (int j=0;j<2;j++) acc[i][j] = (floatx4){0.f,0.f,0.f,0.f};

  #pragma unroll
  for (int kc = 0; kc < 8; kc++){
    short8 af[4], bfr[2];
    #pragma unroll
    for (int i=0;i<4;i++)
      af[i] = *(const short8*)&buf[(i*16 + r16) * LSTR + kc*32 + qd*8];
    #pragma unroll
    for (int j=0;j<2;j++)
      bfr[j] = *(const short8*)(W1P + (size_t)(((w*2 + j)*8 + kc)*64 + lane)*8);
    #pragma unroll
    for (int i=0;i<4;i++)
      #pragma unroll
      for (int j=0;j<2;j++)
        acc[i][j] = __builtin_amdgcn_mfma_f32_16x16x32_bf16(af[i], bfr[j], acc[i][j], 0, 0, 0);
  }
  __syncthreads();

  // ---- ELU -> t tile in same LDS ----
  #pragma unroll
  for (int i=0;i<4;i++){
    #pragma unroll
    for (int j=0;j<2;j++){
      int col = col0 + j*16 + r16;
      float bb = b1[col];
      #pragma unroll
      for (int rr=0;rr<4;rr++){
        int row = i*16 + qd*4 + rr;
        float v = acc[i][j][rr] + bb;
        v = v > 0.f ? v : (__expf(v) - 1.0f);
        buf[row * LSTR + col] = f2bf(v);
      }
    }
  }
  __syncthreads();

  // ---- GEMM2 ----
  #pragma unroll
  for (int i=0;i<4;i++)
    #pragma unroll
    for (int j=0;j<2;j++) acc[i][j] = (floatx4){0.f,0.f,0.f,0.f};

  #pragma unroll
  for (int kc = 0; kc < 8; kc++){
    short8 af[4], bfr[2];
    #pragma unroll
    for (int i=0;i<4;i++)
      af[i] = *(const short8*)&buf[(i*16 + r16) * LSTR + kc*32 + qd*8];
    #pragma unroll
    for (int j=0;j<2;j++)
      bfr[j] = *(const short8*)(W2P + (size_t)(((w*2 + j)*8 + kc)*64 + lane)*8);
    #pragma unroll
    for (int i=0;i<4;i++)
      #pragma unroll
      for (int j=0;j<2;j++)
        acc[i][j] = __builtin_amdgcn_mfma_f32_16x16x32_bf16(af[i], bfr[j], acc[i][j], 0, 0, 0);
  }

  #pragma unroll
  for (int i=0;i<4;i++){
    #pragma unroll
    for (int j=0;j<2;j++){
      int col = col0 + j*16 + r16;
      float bb = b2[col];
      #pragma unroll
      for (int rr=0;rr<4;rr++){
        int row = row0 + i*16 + qd*4 + rr;
        if (row < M) hfeat[(size_t)row * 256 + col] = f2bf(acc[i][j][rr] + bb);
      }
    }
  }
}

// ================= LSTM layer: gates GEMM (K-split x4 waves) + fused cell =================
// 128 blocks x 256. Block = (m0 = 16 rows, nt = 16 h-cols) x 4 gates. Weights fragment-major.
__global__ __launch_bounds__(256) void lstm_layer(const ushort_t* __restrict__ A, int lda,
    const ushort_t* __restrict__ WcP, const float* __restrict__ bcp, int KC,
    float* __restrict__ c, ushort_t* __restrict__ dstA, int sA,
    ushort_t* __restrict__ dstB, int sB, float* __restrict__ qdst)
{
  __shared__ float sbuf[3][4][256];
  int tid = threadIdx.x, w = tid >> 6, lane = tid & 63, qd = lane >> 4, r16 = lane & 15;
  int m0 = (blockIdx.x & 7) * 16, nt = blockIdx.x >> 3;
  int kcq = KC >> 2;                       // chunks per wave: 6 (K=768) or 4 (K=512)
  int kc0 = w * kcq;

  floatx4 acc[4];
  #pragma unroll
  for (int g=0; g<4; g++) acc[g] = (floatx4){0.f,0.f,0.f,0.f};

  const ushort_t* Ar = A + (size_t)(m0 + r16) * lda + qd * 8;
  for (int kc = kc0; kc < kc0 + kcq; kc++){
    short8 av = *(const short8*)(Ar + kc*32);
    #pragma unroll
    for (int g = 0; g < 4; g++){
      short8 bv = *(const short8*)(WcP + (size_t)((((g*16 + nt)*KC) + kc)*64 + lane)*8);
      acc[g] = __builtin_amdgcn_mfma_f32_16x16x32_bf16(av, bv, acc[g], 0, 0, 0);
    }
  }
  if (w){
    #pragma unroll
    for (int g=0; g<4; g++) *(floatx4*)&sbuf[w-1][g][lane*4] = acc[g];
  }
  __syncthreads();
  if (w == 0){
    #pragma unroll
    for (int g=0; g<4; g++)
      #pragma unroll
      for (int t=0; t<3; t++){
        floatx4 p = *(floatx4*)&sbuf[t][g][lane*4];
        acc[g] = acc[g] + p;
      }
    int h = nt*16 + r16;
    float bci = bcp[h], bcf = bcp[256+h], bcg = bcp[512+h], bco = bcp[768+h];
    #pragma unroll
    for (int rr=0; rr<4; rr++){
      int row = m0 + qd*4 + rr;
      float gi = acc[0][rr] + bci;
      float gf = acc[1][rr] + bcf;
      float gg = acc[2][rr] + bcg;
      float go = acc[3][rr] + bco;
      float cp = c[row*256 + h];
      float cn = sigf(gf)*cp + sigf(gi)*tanhf(gg);
      float hn = sigf(go)*tanhf(cn);
      c[row*256 + h] = cn;
      ushort_t hb = f2bf(hn);
      dstA[row*sA + h] = hb;
      dstB[row*sB + h] = hb;
      if (qdst) qdst[row*512 + h] = hn;
    }
  }
}

// ================= segment-owned attention: no atomics, no bidx =================
// 512 blocks x 256 thr; block = (segment b = blockIdx>>2, quarter p = blockIdx&3) via seg[].
// 4 waves node-interleaved (stride 4), x2 unrolled (two independent shfl chains), depth-2
// pair prefetch. Per-block partial -> r_part[p][b][256] / z_part[p][b] (plain stores; fin
// sums the 4 partials). Replaces boundary-scan + ~1M fp32 atomics/step of the old version.
__global__ __launch_bounds__(256) void attn_onepass(const ushort_t* __restrict__ hfeat,
    const int* __restrict__ seg, const float* __restrict__ q_star,
    float* __restrict__ r_part, float* __restrict__ z_part)
{
  __shared__ float sred[4][260];
  int b = blockIdx.x >> 2, p = blockIdx.x & 3;
  int w = threadIdx.x >> 6, lane = threadIdx.x & 63;
  int s0 = seg[b], s1 = seg[b+1];
  int len = s1 - s0;
  int q0 = s0 + ((len * p) >> 2);
  int q1 = s0 + ((len * (p+1)) >> 2);

  float S0=0.f, S1=0.f, S2=0.f, S3=0.f, Z=0.f;

  int n = q0 + w;
  if (n < q1){
    float4 q = *(const float4*)(q_star + (size_t)b*512 + lane*4);
    #define LOADH(nn) (*(const ushort4*)(hfeat + (size_t)(nn)*256 + lane*4))
    ushort4 ha = LOADH(n);
    ushort4 hb = ha;
    if (n + 4 < q1) hb = LOADH(n + 4);
    for (; n < q1; n += 8){
      // prefetch next pair (wave-uniform guards)
      ushort4 hc = ha, hd = hb;
      if (n + 8  < q1) hc = LOADH(n + 8);
      if (n + 12 < q1) hd = LOADH(n + 12);
      // two independent dot+reduce chains
      float a0=bf2f(ha.x), a1=bf2f(ha.y), a2=bf2f(ha.z), a3=bf2f(ha.w);
      float da = a0*q.x + a1*q.y + a2*q.z + a3*q.w;
      float b0=0.f,b1=0.f,b2=0.f,b3=0.f, db=0.f;
      int vB = (n + 4) < q1;
      if (vB){
        b0=bf2f(hb.x); b1=bf2f(hb.y); b2=bf2f(hb.z); b3=bf2f(hb.w);
        db = b0*q.x + b1*q.y + b2*q.z + b3*q.w;
      }
      #pragma unroll
      for (int off = 32; off; off >>= 1){
        da += __shfl_xor(da, off);
        db += __shfl_xor(db, off);
      }
      float wa = __expf(da);
      Z += wa; S0 += wa*a0; S1 += wa*a1; S2 += wa*a2; S3 += wa*a3;
      if (vB){
        float wb = __expf(db);
        Z += wb; S0 += wb*b0; S1 += wb*b1; S2 += wb*b2; S3 += wb*b3;
      }
      ha = hc; hb = hd;
    }
    #undef LOADH
  }

  // block reduce (4 waves) -> one partial store, no atomics
  *(float4*)&sred[w][lane*4] = (float4){S0, S1, S2, S3};
  if (lane == 0) sred[w][256] = Z;
  __syncthreads();
  int f = threadIdx.x;
  if (f < 256){
    float v = sred[0][f] + sred[1][f] + sred[2][f] + sred[3][f];
    r_part[((size_t)p*128 + b)*256 + f] = v;
    if (f == 0)
      z_part[p*128 + b] = sred[0][256] + sred[1][256] + sred[2][256] + sred[3][256];
  }
}

// ================= finalize: r = sum(partials)/Z -> q_star/xc0; last: output GEMM =================
__global__ __launch_bounds__(256) void attn_fin(const float* __restrict__ r_part,
    const float* __restrict__ z_part, float* __restrict__ q_star, ushort_t* __restrict__ xc0,
    const float* __restrict__ outW, const float* __restrict__ outb,
    float* __restrict__ out, int last)
{
  __shared__ float qs[512];
  int b = blockIdx.x, f = threadIdx.x;
  float s = r_part[((size_t)b)*256 + f]
          + r_part[((size_t)(128 + b))*256 + f]
          + r_part[((size_t)(256 + b))*256 + f]
          + r_part[((size_t)(384 + b))*256 + f];
  float z = z_part[b] + z_part[128 + b] + z_part[256 + b] + z_part[384 + b];
  float v = s / (z + 1e-16f);
  q_star[b*512 + 256 + f] = v;
  xc0[b*768 + 256 + f] = f2bf(v);
  if (last){
    qs[f] = q_star[b*512 + f];     // q half (written by lstm2, prior dispatch)
    qs[256 + f] = v;               // r half (computed here)
    __syncthreads();
    if (f < 128){
      float acc = outb[f];
      for (int k = 0; k < 512; k++) acc += qs[k] * outW[k*128 + f];
      out[b*128 + f] = acc;
    }
  }
}

// ================= prep: fragment-major weight packing + all zero/init =================
// Packed layout per 16-col tile T, 32-k chunk kc: [(T*KC + kc)*64 + lane]*8 + j,
// where lane holds BT[n = T*16 + (lane&15)][k = kc*32 + (lane>>4)*8 + j].
__global__ void prep_all(const float* __restrict__ W1, const float* __restrict__ W2,
    const float* __restrict__ Wih0, const float* __restrict__ Whh0,
    const float* __restrict__ Wih1, const float* __restrict__ Whh1,
    const float* __restrict__ Wih2, const float* __restrict__ Whh2,
    const float* __restrict__ bih0, const float* __restrict__ bhh0,
    const float* __restrict__ bih1, const float* __restrict__ bhh1,
    const float* __restrict__ bih2, const float* __restrict__ bhh2,
    const int* __restrict__ bidx,
    ushort_t* __restrict__ W1P, ushort_t* __restrict__ W2P,
    ushort_t* __restrict__ Wc0P, ushort_t* __restrict__ Wc1P, ushort_t* __restrict__ Wc2P,
    float* __restrict__ c, ushort_t* __restrict__ xc, float* __restrict__ q_star,
    float* __restrict__ bc, int* __restrict__ seg)
{
  int i = blockIdx.x*256 + threadIdx.x;
  // --- W1P / W2P: K=256, KC=8, tile size 4096 ---
  if (i < 131072){
    const float* W = (i < 65536) ? W1 : W2;
    ushort_t* P = (i < 65536) ? W1P : W2P;
    int r = i & 65535;
    int T = r >> 12, r2 = r & 4095;
    int kc = r2 >> 9, l = (r2 >> 3) & 63, j = r2 & 7;
    int k = kc*32 + ((l>>4)<<3) + j;
    int n = T*16 + (l & 15);
    P[r] = f2bf(W[k*256 + n]);
    return;
  }
  i -= 131072;
  // --- Wc0P: K=768, KC=24, tile size 12288, 64 tiles ---
  if (i < 786432){
    int T = i / 12288, r2 = i - T*12288;
    int kc = r2 >> 9, l = (r2 >> 3) & 63, j = r2 & 7;
    int k = kc*32 + ((l>>4)<<3) + j;
    int g = T >> 4, n = (T & 15)*16 + (l & 15);
    int row = g*256 + n;
    Wc0P[i] = f2bf(k < 512 ? Wih0[row*512 + k] : Whh0[row*256 + (k - 512)]);
    return;
  }
  i -= 786432;
  // --- Wc1P / Wc2P: K=512, KC=16, tile size 8192, 64 tiles each ---
  if (i < 1048576){
    const float* Wih = (i < 524288) ? Wih1 : Wih2;
    const float* Whh = (i < 524288) ? Whh1 : Whh2;
    ushort_t* P = (i < 524288) ? Wc1P : Wc2P;
    int r = i & 524287;
    int T = r >> 13, r2 = r & 8191;
    int kc = r2 >> 9, l = (r2 >> 3) & 63, j = r2 & 7;
    int k = kc*32 + ((l>>4)<<3) + j;
    int g = T >> 4, n = (T & 15)*16 + (l & 15);
    int row = g*256 + n;
    P[r] = f2bf(k < 256 ? Wih[row*256 + k] : Whh[row*256 + (k - 256)]);
    return;
  }
  i -= 1048576;
  if (i < 98304) { c[i] = 0.f; return; }
  i -= 98304;
  if (i < 229376) { xc[i] = 0; return; }
  i -= 229376;
  if (i < 65536) { q_star[i] = 0.f; return; }
  i -= 65536;
  if (i < 3072) {
    int l = i >> 10, g = i & 1023;
    const float* bi = (l == 0) ? bih0 : ((l == 1) ? bih1 : bih2);
    const float* bh = (l == 0) ? bhh0 : ((l == 1) ? bhh1 : bhh2);
    bc[i] = bi[g] + bh[g];
    return;
  }
  i -= 3072;
  if (i < 129) {
    int lo = 0, hi = NN;
    while (lo < hi){ int mid = (lo + hi) >> 1; if (bidx[mid] < i) lo = mid + 1; else hi = mid; }
    seg[i] = lo;
    return;
  }
}

extern "C" void kernel_launch(void* const* d_in, const int* in_sizes, int n_in,
                              void* d_out, int out_size, void* d_ws, size_t ws_size,
                              hipStream_t stream)
{
  const float* x    = (const float*)d_in[0];
  const int*   bidx = (const int*)  d_in[1];
  const float* W1   = (const float*)d_in[2];
  const float* b1   = (const float*)d_in[3];
  const float* W2   = (const float*)d_in[4];
  const float* b2   = (const float*)d_in[5];
  const float* Wih0 = (const float*)d_in[6];
  const float* Whh0 = (const float*)d_in[7];
  const float* bih0 = (const float*)d_in[8];
  const float* bhh0 = (const float*)d_in[9];
  const float* Wih1 = (const float*)d_in[10];
  const float* Whh1 = (const float*)d_in[11];
  const float* bih1 = (const float*)d_in[12];
  const float* bhh1 = (const float*)d_in[13];
  const float* Wih2 = (const float*)d_in[14];
  const float* Whh2 = (const float*)d_in[15];
  const float* bih2 = (const float*)d_in[16];
  const float* bhh2 = (const float*)d_in[17];
  const float* outW = (const float*)d_in[18];
  const float* outb = (const float*)d_in[19];

  char* p = (char*)d_ws;
  auto alloc = [&](size_t bytes)->char*{ char* r = p; p += (bytes + 255) & ~(size_t)255; return r; };
  ushort_t* hfeat  = (ushort_t*)alloc((size_t)NN*256*2);   // bf16 node features
  ushort_t* W1P    = (ushort_t*)alloc(65536*2);
  ushort_t* W2P    = (ushort_t*)alloc(65536*2);
  ushort_t* Wc0P   = (ushort_t*)alloc(786432*2);
  ushort_t* Wc1P   = (ushort_t*)alloc(524288*2);
  ushort_t* Wc2P   = (ushort_t*)alloc(524288*2);
  float*    bc     = (float*)   alloc(3072*4);
  float*    c_all  = (float*)   alloc(98304*4);
  ushort_t* xc     = (ushort_t*)alloc(229376*2);           // xc0(128x768)|xc1(128x512)|xc2(128x512)
  float*    q_star = (float*)   alloc(65536*4);            // (128,512) fp32
  float*    r_part = (float*)   alloc(4*128*256*4);        // per-quarter attention partials
  float*    z_part = (float*)   alloc(4*128*4);
  int*      seg    = (int*)     alloc(129*4);

  ushort_t* xc0 = xc;
  ushort_t* xc1 = xc + 98304;
  ushort_t* xc2 = xc + 163840;
  float* c0 = c_all, *c1 = c_all + 32768, *c2 = c_all + 65536;
  float* bc0 = bc, *bc1 = bc + 1024, *bc2 = bc + 2048;

  prep_all<<<9229, 256, 0, stream>>>(W1, W2, Wih0, Whh0, Wih1, Whh1, Wih2, Whh2,
                                     bih0, bhh0, bih1, bhh1, bih2, bhh2, bidx,
                                     W1P, W2P, Wc0P, Wc1P, Wc2P,
                                     c_all, xc, q_star, bc, seg);

  fnn_fused<<<1563, 512, 0, stream>>>(x, W1P, b1, W2P, b2, hfeat, NN);

  for (int s = 0; s < NSTEP; s++){
    // layer 0: in = [q_star | h0_prev] (K=768, KC=24)
    lstm_layer<<<128, 256, 0, stream>>>(xc0, 768, Wc0P, bc0, 24, c0, xc0 + 512, 768, xc1, 512, nullptr);
    // layer 1: in = [h0 | h1_prev] (K=512, KC=16)
    lstm_layer<<<128, 256, 0, stream>>>(xc1, 512, Wc1P, bc1, 16, c1, xc1 + 256, 512, xc2, 512, nullptr);
    // layer 2: in = [h1 | h2_prev] (K=512); h2 = q
    lstm_layer<<<128, 256, 0, stream>>>(xc2, 512, Wc2P, bc2, 16, c2, xc2 + 256, 512, xc0, 768, q_star);
    // segment-owned attention + finalize (last step folds in the output GEMM)
    attn_onepass<<<512, 256, 0, stream>>>(hfeat, seg, q_star, r_part, z_part);
    attn_fin<<<128, 256, 0, stream>>>(r_part, z_part, q_star, xc0, outW, outb,
                                      (float*)d_out, s == NSTEP-1 ? 1 : 0);
  }
}

// Round 4
// 414.552 us; speedup vs baseline: 1.4436x; 1.0593x over previous
//
#include <hip/hip_runtime.h>

#define NN 100000
#define NSTEP 5
#define LSTR 264   // ushorts; 528B rows, 16B aligned for ds_read_b128

typedef unsigned short ushort_t;
typedef __attribute__((ext_vector_type(8))) short short8;
typedef __attribute__((ext_vector_type(4))) float floatx4;

__device__ __forceinline__ ushort_t f2bf(float f){
  union { float f; unsigned u; } v; v.f = f;
  unsigned r = v.u + 0x7fffu + ((v.u >> 16) & 1u);
  return (ushort_t)(r >> 16);
}
__device__ __forceinline__ float bf2f(ushort_t s){
  union { unsigned u; float f; } v; v.u = ((unsigned)s) << 16;
  return v.f;
}
__device__ __forceinline__ float sigf(float x){ return 1.0f/(1.0f+__expf(-x)); }

// ================= fused FNN: hfeat = (elu(x@W1+b1))@W2+b2, bf16 out =================
// 1563 blocks x 512 thr (8 waves), 64 rows x 256 cols, 33.8 KB LDS.
// __launch_bounds__(512, 4): min 4 waves/SIMD = 16 waves/CU = 2 blocks (same residency as
// measured) but a 128-reg/wave budget (~96 VGPR + 32 AGPR acc). R1/R3 proved the allocator
// otherwise targets 8 waves/SIMD -> 36 VGPR -> ZERO loads in flight (dur pinned at 78us,
// all pipes <21%). xv[8] is transient (dies at the staging barrier) to avoid R2's spill.
__global__ __launch_bounds__(512, 4) void fnn_fused(const float* __restrict__ x,
    const ushort_t* __restrict__ W1P, const float* __restrict__ b1,
    const ushort_t* __restrict__ W2P, const float* __restrict__ b2,
    ushort_t* __restrict__ hfeat, int M)
{
  __shared__ ushort_t buf[64 * LSTR];
  int tid = threadIdx.x;
  int w = tid >> 6, lane = tid & 63, qd = lane >> 4, r16 = lane & 15;
  int row0 = blockIdx.x * 64;
  int col0 = w * 32;

  // ---- stage x tile: issue all 8 loads, then convert (xv dies before GEMM1) ----
  {
    float4 xv[8];
    #pragma unroll
    for (int it = 0; it < 8; it++){
      int idx = it * 512 + tid;
      int rg = row0 + (idx >> 6); if (rg >= M) rg = M - 1;
      xv[it] = *(const float4*)(x + (size_t)rg * 256 + (idx & 63) * 4);
    }
    #pragma unroll
    for (int it = 0; it < 8; it++){
      int idx = it * 512 + tid;
      ushort4 pk = make_ushort4(f2bf(xv[it].x), f2bf(xv[it].y), f2bf(xv[it].z), f2bf(xv[it].w));
      *(ushort4*)&buf[(idx >> 6) * LSTR + (idx & 63) * 4] = pk;
    }
  }
  __syncthreads();

  floatx4 acc[4][2];

  // ---- GEMM1 ----
  #pragma unroll
  for (int i=0;i<4;i++)
    #pragma unroll
    for (int j=0;j<2;j++) acc[i][j] = (floatx4){0.f,0.f,0.f,0.f};

  #pragma unroll
  for (int kc = 0; kc < 8; kc++){
    short8 af[4], bfr[2];
    #pragma unroll
    for (int i=0;i<4;i++)
      af[i] = *(const short8*)&buf[(i*16 + r16) * LSTR + kc*32 + qd*8];
    #pragma unroll
    for (int j=0;j<2;j++)
      bfr[j] = *(const short8*)(W1P + (size_t)(((w*2 + j)*8 + kc)*64 + lane)*8);
    #pragma unroll
    for (int i=0;i<4;i++)
      #pragma unroll
      for (int j=0;j<2;j++)
        acc[i][j] = __builtin_amdgcn_mfma_f32_16x16x32_bf16(af[i], bfr[j], acc[i][j], 0, 0, 0);
  }
  __syncthreads();

  // ---- ELU -> t tile in same LDS ----
  #pragma unroll
  for (int i=0;i<4;i++){
    #pragma unroll
    for (int j=0;j<2;j++){
      int col = col0 + j*16 + r16;
      float bb = b1[col];
      #pragma unroll
      for (int rr=0;rr<4;rr++){
        int row = i*16 + qd*4 + rr;
        float v = acc[i][j][rr] + bb;
        v = v > 0.f ? v : (__expf(v) - 1.0f);
        buf[row * LSTR + col] = f2bf(v);
      }
    }
  }
  __syncthreads();

  // ---- GEMM2 ----
  #pragma unroll
  for (int i=0;i<4;i++)
    #pragma unroll
    for (int j=0;j<2;j++) acc[i][j] = (floatx4){0.f,0.f,0.f,0.f};

  #pragma unroll
  for (int kc = 0; kc < 8; kc++){
    short8 af[4], bfr[2];
    #pragma unroll
    for (int i=0;i<4;i++)
      af[i] = *(const short8*)&buf[(i*16 + r16) * LSTR + kc*32 + qd*8];
    #pragma unroll
    for (int j=0;j<2;j++)
      bfr[j] = *(const short8*)(W2P + (size_t)(((w*2 + j)*8 + kc)*64 + lane)*8);
    #pragma unroll
    for (int i=0;i<4;i++)
      #pragma unroll
      for (int j=0;j<2;j++)
        acc[i][j] = __builtin_amdgcn_mfma_f32_16x16x32_bf16(af[i], bfr[j], acc[i][j], 0, 0, 0);
  }

  #pragma unroll
  for (int i=0;i<4;i++){
    #pragma unroll
    for (int j=0;j<2;j++){
      int col = col0 + j*16 + r16;
      float bb = b2[col];
      #pragma unroll
      for (int rr=0;rr<4;rr++){
        int row = row0 + i*16 + qd*4 + rr;
        if (row < M) hfeat[(size_t)row * 256 + col] = f2bf(acc[i][j][rr] + bb);
      }
    }
  }
}

// ================= LSTM layer: gates GEMM (K-split x4 waves) + fused cell =================
// 128 blocks x 256. Block = (m0 = 16 rows, nt = 16 h-cols) x 4 gates. Weights fragment-major.
__global__ __launch_bounds__(256) void lstm_layer(const ushort_t* __restrict__ A, int lda,
    const ushort_t* __restrict__ WcP, const float* __restrict__ bcp, int KC,
    float* __restrict__ c, ushort_t* __restrict__ dstA, int sA,
    ushort_t* __restrict__ dstB, int sB, float* __restrict__ qdst)
{
  __shared__ float sbuf[3][4][256];
  int tid = threadIdx.x, w = tid >> 6, lane = tid & 63, qd = lane >> 4, r16 = lane & 15;
  int m0 = (blockIdx.x & 7) * 16, nt = blockIdx.x >> 3;
  int kcq = KC >> 2;                       // chunks per wave: 6 (K=768) or 4 (K=512)
  int kc0 = w * kcq;

  floatx4 acc[4];
  #pragma unroll
  for (int g=0; g<4; g++) acc[g] = (floatx4){0.f,0.f,0.f,0.f};

  const ushort_t* Ar = A + (size_t)(m0 + r16) * lda + qd * 8;
  for (int kc = kc0; kc < kc0 + kcq; kc++){
    short8 av = *(const short8*)(Ar + kc*32);
    #pragma unroll
    for (int g = 0; g < 4; g++){
      short8 bv = *(const short8*)(WcP + (size_t)((((g*16 + nt)*KC) + kc)*64 + lane)*8);
      acc[g] = __builtin_amdgcn_mfma_f32_16x16x32_bf16(av, bv, acc[g], 0, 0, 0);
    }
  }
  if (w){
    #pragma unroll
    for (int g=0; g<4; g++) *(floatx4*)&sbuf[w-1][g][lane*4] = acc[g];
  }
  __syncthreads();
  if (w == 0){
    #pragma unroll
    for (int g=0; g<4; g++)
      #pragma unroll
      for (int t=0; t<3; t++){
        floatx4 p = *(floatx4*)&sbuf[t][g][lane*4];
        acc[g] = acc[g] + p;
      }
    int h = nt*16 + r16;
    float bci = bcp[h], bcf = bcp[256+h], bcg = bcp[512+h], bco = bcp[768+h];
    #pragma unroll
    for (int rr=0; rr<4; rr++){
      int row = m0 + qd*4 + rr;
      float gi = acc[0][rr] + bci;
      float gf = acc[1][rr] + bcf;
      float gg = acc[2][rr] + bcg;
      float go = acc[3][rr] + bco;
      float cp = c[row*256 + h];
      float cn = sigf(gf)*cp + sigf(gi)*tanhf(gg);
      float hn = sigf(go)*tanhf(cn);
      c[row*256 + h] = cn;
      ushort_t hb = f2bf(hn);
      dstA[row*sA + h] = hb;
      dstB[row*sB + h] = hb;
      if (qdst) qdst[row*512 + h] = hn;
    }
  }
}

// ================= segment-owned attention: no atomics, no bidx =================
// 1024 blocks x 256 thr; block = (segment b = blockIdx>>3, eighth p = blockIdx&7) via seg[].
// 4 blocks/CU -> 16 waves/CU; 2-pair prefetch/wave => ~32KB in flight per CU (>= ~22KB
// BW-latency product) so the 51.2MB hfeat stream can run near the HBM floor (~8us/dispatch).
// Per-block partial -> r_part[p][b][256] / z_part[p][b]; fin sums the 8 partials.
__global__ __launch_bounds__(256) void attn_onepass(const ushort_t* __restrict__ hfeat,
    const int* __restrict__ seg, const float* __restrict__ q_star,
    float* __restrict__ r_part, float* __restrict__ z_part)
{
  __shared__ float sred[4][260];
  int b = blockIdx.x >> 3, p = blockIdx.x & 7;
  int w = threadIdx.x >> 6, lane = threadIdx.x & 63;
  int s0 = seg[b], s1 = seg[b+1];
  int len = s1 - s0;
  int q0 = s0 + ((len * p) >> 3);
  int q1 = s0 + ((len * (p+1)) >> 3);

  float S0=0.f, S1=0.f, S2=0.f, S3=0.f, Z=0.f;

  int n = q0 + w;
  if (n < q1){
    float4 q = *(const float4*)(q_star + (size_t)b*512 + lane*4);
    #define LOADH(nn) (*(const ushort4*)(hfeat + (size_t)(nn)*256 + lane*4))
    ushort4 ha = LOADH(n);
    ushort4 hb = ha;
    if (n + 4 < q1) hb = LOADH(n + 4);
    for (; n < q1; n += 8){
      // prefetch next pair (wave-uniform guards)
      ushort4 hc = ha, hd = hb;
      if (n + 8  < q1) hc = LOADH(n + 8);
      if (n + 12 < q1) hd = LOADH(n + 12);
      // two independent dot+reduce chains
      float a0=bf2f(ha.x), a1=bf2f(ha.y), a2=bf2f(ha.z), a3=bf2f(ha.w);
      float da = a0*q.x + a1*q.y + a2*q.z + a3*q.w;
      float b0=0.f,b1=0.f,b2=0.f,b3=0.f, db=0.f;
      int vB = (n + 4) < q1;
      if (vB){
        b0=bf2f(hb.x); b1=bf2f(hb.y); b2=bf2f(hb.z); b3=bf2f(hb.w);
        db = b0*q.x + b1*q.y + b2*q.z + b3*q.w;
      }
      #pragma unroll
      for (int off = 32; off; off >>= 1){
        da += __shfl_xor(da, off);
        db += __shfl_xor(db, off);
      }
      float wa = __expf(da);
      Z += wa; S0 += wa*a0; S1 += wa*a1; S2 += wa*a2; S3 += wa*a3;
      if (vB){
        float wb = __expf(db);
        Z += wb; S0 += wb*b0; S1 += wb*b1; S2 += wb*b2; S3 += wb*b3;
      }
      ha = hc; hb = hd;
    }
    #undef LOADH
  }

  // block reduce (4 waves) -> one partial store, no atomics
  *(float4*)&sred[w][lane*4] = (float4){S0, S1, S2, S3};
  if (lane == 0) sred[w][256] = Z;
  __syncthreads();
  int f = threadIdx.x;
  if (f < 256){
    float v = sred[0][f] + sred[1][f] + sred[2][f] + sred[3][f];
    r_part[((size_t)p*128 + b)*256 + f] = v;
    if (f == 0)
      z_part[p*128 + b] = sred[0][256] + sred[1][256] + sred[2][256] + sred[3][256];
  }
}

// ================= finalize: r = sum(partials)/Z -> q_star/xc0; last: output GEMM =================
__global__ __launch_bounds__(256) void attn_fin(const float* __restrict__ r_part,
    const float* __restrict__ z_part, float* __restrict__ q_star, ushort_t* __restrict__ xc0,
    const float* __restrict__ outW, const float* __restrict__ outb,
    float* __restrict__ out, int last)
{
  __shared__ float qs[512];
  int b = blockIdx.x, f = threadIdx.x;
  float s = 0.f, z = 0.f;
  #pragma unroll
  for (int t = 0; t < 8; t++){
    s += r_part[((size_t)(t*128 + b))*256 + f];
    z += z_part[t*128 + b];
  }
  float v = s / (z + 1e-16f);
  q_star[b*512 + 256 + f] = v;
  xc0[b*768 + 256 + f] = f2bf(v);
  if (last){
    qs[f] = q_star[b*512 + f];     // q half (written by lstm2, prior dispatch)
    qs[256 + f] = v;               // r half (computed here)
    __syncthreads();
    if (f < 128){
      float acc = outb[f];
      for (int k = 0; k < 512; k++) acc += qs[k] * outW[k*128 + f];
      out[b*128 + f] = acc;
    }
  }
}

// ================= prep: fragment-major weight packing + all zero/init =================
// Packed layout per 16-col tile T, 32-k chunk kc: [(T*KC + kc)*64 + lane]*8 + j,
// where lane holds BT[n = T*16 + (lane&15)][k = kc*32 + (lane>>4)*8 + j].
__global__ void prep_all(const float* __restrict__ W1, const float* __restrict__ W2,
    const float* __restrict__ Wih0, const float* __restrict__ Whh0,
    const float* __restrict__ Wih1, const float* __restrict__ Whh1,
    const float* __restrict__ Wih2, const float* __restrict__ Whh2,
    const float* __restrict__ bih0, const float* __restrict__ bhh0,
    const float* __restrict__ bih1, const float* __restrict__ bhh1,
    const float* __restrict__ bih2, const float* __restrict__ bhh2,
    const int* __restrict__ bidx,
    ushort_t* __restrict__ W1P, ushort_t* __restrict__ W2P,
    ushort_t* __restrict__ Wc0P, ushort_t* __restrict__ Wc1P, ushort_t* __restrict__ Wc2P,
    float* __restrict__ c, ushort_t* __restrict__ xc, float* __restrict__ q_star,
    float* __restrict__ bc, int* __restrict__ seg)
{
  int i = blockIdx.x*256 + threadIdx.x;
  // --- W1P / W2P: K=256, KC=8, tile size 4096 ---
  if (i < 131072){
    const float* W = (i < 65536) ? W1 : W2;
    ushort_t* P = (i < 65536) ? W1P : W2P;
    int r = i & 65535;
    int T = r >> 12, r2 = r & 4095;
    int kc = r2 >> 9, l = (r2 >> 3) & 63, j = r2 & 7;
    int k = kc*32 + ((l>>4)<<3) + j;
    int n = T*16 + (l & 15);
    P[r] = f2bf(W[k*256 + n]);
    return;
  }
  i -= 131072;
  // --- Wc0P: K=768, KC=24, tile size 12288, 64 tiles ---
  if (i < 786432){
    int T = i / 12288, r2 = i - T*12288;
    int kc = r2 >> 9, l = (r2 >> 3) & 63, j = r2 & 7;
    int k = kc*32 + ((l>>4)<<3) + j;
    int g = T >> 4, n = (T & 15)*16 + (l & 15);
    int row = g*256 + n;
    Wc0P[i] = f2bf(k < 512 ? Wih0[row*512 + k] : Whh0[row*256 + (k - 512)]);
    return;
  }
  i -= 786432;
  // --- Wc1P / Wc2P: K=512, KC=16, tile size 8192, 64 tiles each ---
  if (i < 1048576){
    const float* Wih = (i < 524288) ? Wih1 : Wih2;
    const float* Whh = (i < 524288) ? Whh1 : Whh2;
    ushort_t* P = (i < 524288) ? Wc1P : Wc2P;
    int r = i & 524287;
    int T = r >> 13, r2 = r & 8191;
    int kc = r2 >> 9, l = (r2 >> 3) & 63, j = r2 & 7;
    int k = kc*32 + ((l>>4)<<3) + j;
    int g = T >> 4, n = (T & 15)*16 + (l & 15);
    int row = g*256 + n;
    P[r] = f2bf(k < 256 ? Wih[row*256 + k] : Whh[row*256 + (k - 256)]);
    return;
  }
  i -= 1048576;
  if (i < 98304) { c[i] = 0.f; return; }
  i -= 98304;
  if (i < 229376) { xc[i] = 0; return; }
  i -= 229376;
  if (i < 65536) { q_star[i] = 0.f; return; }
  i -= 65536;
  if (i < 3072) {
    int l = i >> 10, g = i & 1023;
    const float* bi = (l == 0) ? bih0 : ((l == 1) ? bih1 : bih2);
    const float* bh = (l == 0) ? bhh0 : ((l == 1) ? bhh1 : bhh2);
    bc[i] = bi[g] + bh[g];
    return;
  }
  i -= 3072;
  if (i < 129) {
    int lo = 0, hi = NN;
    while (lo < hi){ int mid = (lo + hi) >> 1; if (bidx[mid] < i) lo = mid + 1; else hi = mid; }
    seg[i] = lo;
    return;
  }
}

extern "C" void kernel_launch(void* const* d_in, const int* in_sizes, int n_in,
                              void* d_out, int out_size, void* d_ws, size_t ws_size,
                              hipStream_t stream)
{
  const float* x    = (const float*)d_in[0];
  const int*   bidx = (const int*)  d_in[1];
  const float* W1   = (const float*)d_in[2];
  const float* b1   = (const float*)d_in[3];
  const float* W2   = (const float*)d_in[4];
  const float* b2   = (const float*)d_in[5];
  const float* Wih0 = (const float*)d_in[6];
  const float* Whh0 = (const float*)d_in[7];
  const float* bih0 = (const float*)d_in[8];
  const float* bhh0 = (const float*)d_in[9];
  const float* Wih1 = (const float*)d_in[10];
  const float* Whh1 = (const float*)d_in[11];
  const float* bih1 = (const float*)d_in[12];
  const float* bhh1 = (const float*)d_in[13];
  const float* Wih2 = (const float*)d_in[14];
  const float* Whh2 = (const float*)d_in[15];
  const float* bih2 = (const float*)d_in[16];
  const float* bhh2 = (const float*)d_in[17];
  const float* outW = (const float*)d_in[18];
  const float* outb = (const float*)d_in[19];

  char* p = (char*)d_ws;
  auto alloc = [&](size_t bytes)->char*{ char* r = p; p += (bytes + 255) & ~(size_t)255; return r; };
  ushort_t* hfeat  = (ushort_t*)alloc((size_t)NN*256*2);   // bf16 node features
  ushort_t* W1P    = (ushort_t*)alloc(65536*2);
  ushort_t* W2P    = (ushort_t*)alloc(65536*2);
  ushort_t* Wc0P   = (ushort_t*)alloc(786432*2);
  ushort_t* Wc1P   = (ushort_t*)alloc(524288*2);
  ushort_t* Wc2P   = (ushort_t*)alloc(524288*2);
  float*    bc     = (float*)   alloc(3072*4);
  float*    c_all  = (float*)   alloc(98304*4);
  ushort_t* xc     = (ushort_t*)alloc(229376*2);           // xc0(128x768)|xc1(128x512)|xc2(128x512)
  float*    q_star = (float*)   alloc(65536*4);            // (128,512) fp32
  float*    r_part = (float*)   alloc(8*128*256*4);        // per-eighth attention partials
  float*    z_part = (float*)   alloc(8*128*4);
  int*      seg    = (int*)     alloc(129*4);

  ushort_t* xc0 = xc;
  ushort_t* xc1 = xc + 98304;
  ushort_t* xc2 = xc + 163840;
  float* c0 = c_all, *c1 = c_all + 32768, *c2 = c_all + 65536;
  float* bc0 = bc, *bc1 = bc + 1024, *bc2 = bc + 2048;

  prep_all<<<9229, 256, 0, stream>>>(W1, W2, Wih0, Whh0, Wih1, Whh1, Wih2, Whh2,
                                     bih0, bhh0, bih1, bhh1, bih2, bhh2, bidx,
                                     W1P, W2P, Wc0P, Wc1P, Wc2P,
                                     c_all, xc, q_star, bc, seg);

  fnn_fused<<<1563, 512, 0, stream>>>(x, W1P, b1, W2P, b2, hfeat, NN);

  for (int s = 0; s < NSTEP; s++){
    // layer 0: in = [q_star | h0_prev] (K=768, KC=24)
    lstm_layer<<<128, 256, 0, stream>>>(xc0, 768, Wc0P, bc0, 24, c0, xc0 + 512, 768, xc1, 512, nullptr);
    // layer 1: in = [h0 | h1_prev] (K=512, KC=16)
    lstm_layer<<<128, 256, 0, stream>>>(xc1, 512, Wc1P, bc1, 16, c1, xc1 + 256, 512, xc2, 512, nullptr);
    // layer 2: in = [h1 | h2_prev] (K=512); h2 = q
    lstm_layer<<<128, 256, 0, stream>>>(xc2, 512, Wc2P, bc2, 16, c2, xc2 + 256, 512, xc0, 768, q_star);
    // segment-owned attention + finalize (last step folds in the output GEMM)
    attn_onepass<<<1024, 256, 0, stream>>>(hfeat, seg, q_star, r_part, z_part);
    attn_fin<<<128, 256, 0, stream>>>(r_part, z_part, q_star, xc0, outW, outb,
                                      (float*)d_out, s == NSTEP-1 ? 1 : 0);
  }
}